// Round 5
// baseline (538.035 us; speedup 1.0000x reference)
//
#include <hip/hip_runtime.h>
#include <hip/hip_bf16.h>
#include <math.h>

#define HID   4096
#define NH    32
#define NG    8
#define DH    128
#define SEQ   2048
#define QKV_N 6144   // 4096 q | 1024 k | 1024 v
#define KOFF  4096
#define VOFF  5120

typedef __bf16 bf16x8 __attribute__((ext_vector_type(8)));
typedef float  f32x4  __attribute__((ext_vector_type(4)));
using bf16 = __hip_bfloat16;

#define LOG2E 1.4426950408889634f
#define SCALE 0.08838834764831845f   // 1/sqrt(128)

// ---- async global->LDS 16B (wave-uniform LDS base + lane*16) ----
typedef const __attribute__((address_space(1))) void* gas_p;
typedef __attribute__((address_space(3))) void* las_p;
__device__ __forceinline__ void async_copy16(void* lds, const void* g) {
  __builtin_amdgcn_global_load_lds((gas_p)g, (las_p)lds, 16, 0, 0);
}

__device__ __forceinline__ unsigned pack2(float a, float b) {
  union { bf16 h[2]; unsigned u; } t;
  t.h[0] = __float2bfloat16(a);
  t.h[1] = __float2bfloat16(b);
  return t.u;
}

// ---- unified prepass: weight transposes + X cast + bias concat, ONE launch ----
__global__ __launch_bounds__(256) void prepass_kernel(const float* __restrict__ X,
                                                      const float* __restrict__ Wq, const float* __restrict__ Wk,
                                                      const float* __restrict__ Wv, const float* __restrict__ Wo,
                                                      const float* __restrict__ bq, const float* __restrict__ bk,
                                                      const float* __restrict__ bv,
                                                      bf16* __restrict__ Xb,
                                                      bf16* __restrict__ Wqkv_t, bf16* __restrict__ Wot,
                                                      float* __restrict__ bqkv) {
  const int bx = blockIdx.x, by = blockIdx.y;
  const int t = threadIdx.x;
  if (bx >= 288) {               // bias concat
    if (by < 24) {
      int i = by * 256 + t;
      if (i < 4096)       bqkv[i] = bq[i];
      else if (i < 5120)  bqkv[i] = bk[i - 4096];
      else                bqkv[i] = bv[i - 5120];
    }
    return;
  }
  if (bx >= 160) {               // X cast: float4 per thread
    int i = ((bx - 160) + 128 * by) * 256 + t;
    float4 v = ((const float4*)X)[i];
    union { bf16 h[4]; uint2 u; } c;
    c.h[0] = __float2bfloat16(v.x);
    c.h[1] = __float2bfloat16(v.y);
    c.h[2] = __float2bfloat16(v.z);
    c.h[3] = __float2bfloat16(v.w);
    ((uint2*)Xb)[i] = c.u;
    return;
  }
  __shared__ bf16 T[64][72];
  const float* W; bf16* dst; int N, ntile;
  if (bx < 64)      { W = Wq; dst = Wqkv_t;                      N = 4096; ntile = bx; }
  else if (bx < 80) { W = Wk; dst = Wqkv_t + (size_t)KOFF * HID; N = 1024; ntile = bx - 64; }
  else if (bx < 96) { W = Wv; dst = Wqkv_t + (size_t)VOFF * HID; N = 1024; ntile = bx - 80; }
  else              { W = Wo; dst = Wot;                         N = 4096; ntile = bx - 96; }
  const int n0 = ntile * 64, k0 = by * 64;
  const int nn = (t & 15) * 4, kk = t >> 4;
#pragma unroll
  for (int p = 0; p < 4; ++p) {
    const int k = kk + p * 16;
    float4 v = *(const float4*)&W[(size_t)(k0 + k) * N + n0 + nn];
    union { bf16 h[4]; uint2 u; } c;
    c.h[0] = __float2bfloat16(v.x);
    c.h[1] = __float2bfloat16(v.y);
    c.h[2] = __float2bfloat16(v.z);
    c.h[3] = __float2bfloat16(v.w);
    *(uint2*)&T[k][nn] = c.u;
  }
  __syncthreads();
  const int kc = t & 7, nr = t >> 3;
#pragma unroll
  for (int p = 0; p < 2; ++p) {
    const int n = nr + p * 32;
    union { bf16 h[8]; uint4 u; } o;
#pragma unroll
    for (int i = 0; i < 8; ++i) o.h[i] = T[kc * 8 + i][n];
    *(uint4*)&dst[(size_t)(n0 + n) * HID + k0 + kc * 8] = o.u;
  }
}

// ------- GEMM v5: v3b skeleton + balanced ds_read phases + XCD block swizzle -------
// C[M][N] = A[M][K] @ Bt[N][K]^T + bias.  BN=256, BM in {256,128}. 512 thr = 8 waves
// (wr=w>>2 over M, wc=w&3 over N; per-wave (BM/2) x 64).  BK=64, kh in {0,1}.
// Phases per K-tile (reordered by (kh, m-half) to balance LDS reads; staging,
// barriers, vmcnt ledger and MFMA-count/phase are IDENTICAL to the verified v3b):
//   P0 = kh0,mh0: ldB4 + ldA2(mh0) (8 reads BM=256) ; MFMAs mf[0..MH)  x nf[0..4)
//   P1 = kh0,mh1: ldA2(mh1)        (4 reads)        ; MFMAs mf[MH..MT) x nf[0..4)
//   P2 = kh1,mh0: ldB4 + ldA2(mh0) (8)              ; ...
//   P3 = kh1,mh1: ldA2(mh1)        (4)
// (v3b was 10/2/10/2 -- A-frag reads bunched; LDS pipe burst 320cy vs MFMA 154cy
// per phase.  8/4/8/4 evens the pipe loads so cross-wave overlap covers them.)
// Staging at phase p of kt: one k-half of kt+1 (order A0,B0,A1,B1) into
// buf[(kt+1)&1]; end-of-phase s_waitcnt vmcnt(LA+LB) confirms loads issued 2
// phases earlier; the following barrier publishes them.  JIT availability
// per-half unchanged from v3b (B-kh0 published P3(t-1)-end, read P0(t); A-kh1
// published P0(t)-end, read P2(t); etc).  vmcnt never 0 in loop; vmcnt(0) drain
// before epilogue (no LDS-DMA in flight at s_endpgm).
// XCD swizzle (T1): flat' = (flat&7)*(nwg/8) + (flat>>3), bijective (nwg%8==0:
// QKV 192, out-proj 256).  Each XCD owns a contiguous chunk sharing one A-panel
// -> A stays L2-hot, lower load latency -> counted-vmcnt waits stall less.
// Swizzle (LDS): row r slot s holds global chunk s^((r>>1)&3); applied to the
// pre-swizzled global source (linear LDS-DMA dest) and the ds_read address.
__device__ __forceinline__ void st_out(float* C, size_t idx, float v) { C[idx] = v; }
__device__ __forceinline__ void st_out(bf16*  C, size_t idx, float v) { C[idx] = __float2bfloat16(v); }

template <int BM, typename OutT>
__global__ __launch_bounds__(512, 2) void gemm10_kernel(const bf16* __restrict__ A, const bf16* __restrict__ Bt,
                                                        const float* __restrict__ bias, OutT* __restrict__ C,
                                                        int M, int N, int K) {
  constexpr int MT = BM / 32;                        // M frags per wave (8 or 4)
  constexpr int MH = MT / 2;                         // frags per m-half (4 or 2)
  constexpr int LA = (BM * 32 * 2) / (512 * 16);     // A loads/thread per k-half (2 or 1)
  constexpr int LB = 2;                              // B loads/thread per k-half

  __shared__ alignas(16) bf16 As[2][2][BM * 32];     // [buf][kh][row*32 + slot*8]
  __shared__ alignas(16) bf16 Bs[2][2][256 * 32];

  const int tid = threadIdx.x;
  const int w = tid >> 6, lane = tid & 63, quad = lane >> 4, l16 = lane & 15;
  const int wr = w >> 2, wc = w & 3;

  // XCD-aware bijective block swizzle (requires nwg % 8 == 0)
  const int nwg  = gridDim.x * gridDim.y;
  int flat = blockIdx.y * gridDim.x + blockIdx.x;
  flat = (flat & 7) * (nwg >> 3) + (flat >> 3);
  const int m0 = (flat / gridDim.x) * BM, n0 = (flat % gridDim.x) * 256;

  const bf16* const Ag = A  + (size_t)m0 * K;
  const bf16* const Bg = Bt + (size_t)n0 * K;

  auto stA = [&](int skt, int db, int kh) {
    const int kb = skt * 64 + kh * 32;
#pragma unroll
    for (int L = 0; L < LA; ++L) {
      const int cib = (L * 8 + w) * 64;              // wave-uniform chunk base
      const int ci  = cib + lane;
      const int r   = ci >> 2;
      const int j   = (ci & 3) ^ ((r >> 1) & 3);     // inverse swizzle on source
      async_copy16(&As[db][kh][cib * 8], Ag + (size_t)r * K + kb + j * 8);
    }
  };
  auto stB = [&](int skt, int db, int kh) {
    const int kb = skt * 64 + kh * 32;
#pragma unroll
    for (int L = 0; L < LB; ++L) {
      const int cib = (L * 8 + w) * 64;
      const int ci  = cib + lane;
      const int r   = ci >> 2;
      const int j   = (ci & 3) ^ ((r >> 1) & 3);
      async_copy16(&Bs[db][kh][cib * 8], Bg + (size_t)r * K + kb + j * 8);
    }
  };

  auto waitv = [&]() {   // vmcnt(LA+LB): confirm this thread's loads from 2 phases ago
    if constexpr (BM == 256) asm volatile("s_waitcnt vmcnt(4)" ::: "memory");
    else                     asm volatile("s_waitcnt vmcnt(3)" ::: "memory");
  };

  bf16x8 af2[MH], bf4[4];
  auto ldA2 = [&](int buf, int kh, int mh) {
#pragma unroll
    for (int i = 0; i < MH; ++i) {
      const int r = wr * (BM / 2) + (mh * MH + i) * 16 + l16;
      af2[i] = *(const bf16x8*)&As[buf][kh][r * 32 + ((quad ^ ((r >> 1) & 3)) << 3)];
    }
  };
  auto ldB4 = [&](int buf, int kh) {
#pragma unroll
    for (int j = 0; j < 4; ++j) {
      const int r = wc * 64 + j * 16 + l16;
      bf4[j] = *(const bf16x8*)&Bs[buf][kh][r * 32 + ((quad ^ ((r >> 1) & 3)) << 3)];
    }
  };

  f32x4 acc[MT][4];
  f32x4 zero4 = {0.f, 0.f, 0.f, 0.f};
#pragma unroll
  for (int mf = 0; mf < MT; ++mf)
#pragma unroll
    for (int nf = 0; nf < 4; ++nf) acc[mf][nf] = zero4;

#define GPHASE(BUF, KH, MHH, STAGE_CALL)                                                    \
  do {                                                                                      \
    if (MHH == 0) ldB4(BUF, KH);                                                            \
    ldA2(BUF, KH, MHH);                                                                     \
    STAGE_CALL;                                                                             \
    __builtin_amdgcn_s_barrier();                                                           \
    asm volatile("s_waitcnt lgkmcnt(0)" ::: "memory");                                      \
    __builtin_amdgcn_sched_barrier(0);                                                      \
    __builtin_amdgcn_s_setprio(1);                                                          \
    _Pragma("unroll")                                                                       \
    for (int i = 0; i < MH; ++i) {                                                          \
      _Pragma("unroll")                                                                     \
      for (int nf = 0; nf < 4; ++nf)                                                        \
        acc[MHH * MH + i][nf] =                                                             \
            __builtin_amdgcn_mfma_f32_16x16x32_bf16(af2[i], bf4[nf], acc[MHH * MH + i][nf], 0, 0, 0); \
    }                                                                                       \
    __builtin_amdgcn_s_setprio(0);                                                          \
    waitv();                                                                                \
    __builtin_amdgcn_s_barrier();                                                           \
    asm volatile("" ::: "memory");                                                          \
  } while (0)

  const int KT = K >> 6;                             // BK=64 tiles

  // prologue: stage all 4 halves of kt=0, publish the first two confirmed
  stA(0, 0, 0); stB(0, 0, 0); stA(0, 0, 1); stB(0, 0, 1);
  waitv();
  __builtin_amdgcn_s_barrier();
  asm volatile("" ::: "memory");

  for (int kt = 0; kt < KT; ++kt) {
    const int buf = kt & 1;
    const int nkt = kt + 1;
    const int skt = nkt < KT ? nkt : KT - 1;         // tail: redundant clamped stage keeps ledger uniform
    const int db  = nkt & 1;
    GPHASE(buf, 0, 0, stA(skt, db, 0));
    GPHASE(buf, 0, 1, stB(skt, db, 0));
    GPHASE(buf, 1, 0, stA(skt, db, 1));
    GPHASE(buf, 1, 1, stB(skt, db, 1));
  }
#undef GPHASE

  // drain LDS-DMA before epilogue: no in-flight global_load_lds at s_endpgm
  asm volatile("s_waitcnt vmcnt(0)" ::: "memory");

  // epilogue: bias + store (same fragment->C mapping as verified baseline)
#pragma unroll
  for (int nf = 0; nf < 4; ++nf) {
    const int col = n0 + wc * 64 + nf * 16 + l16;
    const float bv = bias[col];
#pragma unroll
    for (int mf = 0; mf < MT; ++mf) {
#pragma unroll
      for (int r = 0; r < 4; ++r) {
        const int row = m0 + wr * (BM / 2) + mf * 16 + quad * 4 + r;
        st_out(C, (size_t)row * N + col, acc[mf][nf][r] + bv);
      }
    }
  }
}

// ---- fused RoPE (q,k) + V transpose, one launch (disjoint QKV regions) ----
__global__ __launch_bounds__(256) void rope_vtrans_kernel(bf16* __restrict__ qkv, bf16* __restrict__ vt) {
  __shared__ bf16 tle[32][33];
  const int bx = blockIdx.x;
  const int tid = threadIdx.x;
  if (bx < 2560) {
    int t = bx * 256 + tid;
    int c  = t & 7;
    int hs = (t >> 3) % 40;
    int s  = t / 320;
    int base = (hs < 32) ? hs * 128 : KOFF + (hs - 32) * 128;
    bf16* p = qkv + (size_t)s * QKV_N + base + c * 8;
    union { bf16x8 v; bf16 h[8]; } a, b, ra, rb;
    a.v = *(bf16x8*)p;
    b.v = *(bf16x8*)(p + 64);
#pragma unroll
    for (int j = 0; j < 8; ++j) {
      int d = c * 8 + j;
      float inv = expf(d * -0.14391156862f);  // ln(10000)/64
      float ang = (float)s * inv;
      float sn, cs;
      sincosf(ang, &sn, &cs);
      float x1 = __bfloat162float(a.h[j]);
      float x2 = __bfloat162float(b.h[j]);
      ra.h[j] = __float2bfloat16(x1 * cs - x2 * sn);
      rb.h[j] = __float2bfloat16(x1 * sn + x2 * cs);
    }
    *(bf16x8*)p        = ra.v;
    *(bf16x8*)(p + 64) = rb.v;
  } else {
    const int b = bx - 2560;
    const int s0 = (b & 63) * 32, d0 = ((b >> 6) & 3) * 32, g = b >> 8;
    const int tx = tid & 31, ty = tid >> 5;
#pragma unroll
    for (int i = 0; i < 4; ++i)
      tle[ty + i * 8][tx] = qkv[(size_t)(s0 + ty + i * 8) * QKV_N + VOFF + g * 128 + d0 + tx];
    __syncthreads();
#pragma unroll
    for (int i = 0; i < 4; ++i)
      vt[(size_t)(g * 128 + d0 + ty + i * 8) * SEQ + s0 + tx] = tle[tx][ty + i * 8];
  }
}

// ---------------- Flash attention v5: in-block split-KV, 8 waves ----------------
__global__ __launch_bounds__(512, 4) void attn_kernel(const bf16* __restrict__ qkv, const bf16* __restrict__ vt,
                                                      bf16* __restrict__ ctx) {
  __shared__ alignas(16) bf16 Ks[2][2][32][128];  // [gid][buf][key][d] xor-swizzled; 32 KB
  __shared__ alignas(16) bf16 Vs[2][2][64][64];   // [gid][buf][d>>1][(d&1)*32+key] pair-packed; 32 KB
  __shared__ float rs1[64];
  float* const red = (float*)&Ks[0][0][0][0];     // epilogue overlay: 64q x 128d fp32 = 32 KB

  const int bx = blockIdx.x;        // 0..15
  const int h  = blockIdx.y;
  const int g  = h >> 2;
  const int tid = threadIdx.x;
  const int w = tid >> 6;           // 0..7
  const int gid = w >> 2, wq = w & 3;
  const int lane = tid & 63, quad = lane >> 4, l16 = lane & 15;

  const float c1 = SCALE * LOG2E;
  const float c2 = 12.0f * LOG2E;   // fixed max M0 = 12

  const int addrA = (((quad & 1) << 5) + l16) * 4;  // bpermute src (quad pair base)
  const int addrB = addrA + 64;
  const bool hiq = quad >= 2;

  f32x4 zero4 = {0.f, 0.f, 0.f, 0.f};

  auto stage = [&](int kt2, int buf) {
    const int ktg = 2 * kt2 + gid;
    const bf16* kg = qkv + (size_t)(ktg * 32) * QKV_N + KOFF + g * 128;
    const bf16* vg = vt + (size_t)(g * 128) * SEQ + ktg * 32;
#pragma unroll
    for (int i = 0; i < 2; ++i) {
      const int c = (i * 4 + wq) * 64 + lane;    // chunk 0..511
      {  // K: 32 keys x 16 chunks
        const int key = c >> 4, j = c & 15;
        const int js = (j & 8) | ((j ^ key) & 7);
        async_copy16(&Ks[gid][buf][0][0] + (size_t)(i * 4 + wq) * 512,
                     kg + (size_t)key * QKV_N + js * 8);
      }
      {  // V: 64 rows (d-pairs) x 8 chunks; slot k8s holds global chunk (k8s^row)&3
        const int row = c >> 3, d = row * 2 + ((c >> 2) & 1), k8s = c & 3;
        const int vjs = (k8s ^ row) & 3;
        async_copy16(&Vs[gid][buf][0][0] + (size_t)(i * 4 + wq) * 512,
                     vg + (size_t)d * SEQ + vjs * 8);
      }
    }
  };

  for (int ph = 0; ph < 2; ++ph) {
    const int qt = ph ? bx : (31 - bx);

    // Q fragments (B-operand): q = qt*64 + wq*16 + l16, k = ks*32 + quad*8 + j
    bf16x8 qf[4];
    {
      const bf16* qp = qkv + (size_t)(qt * 64 + wq * 16 + l16) * QKV_N + h * 128 + quad * 8;
#pragma unroll
      for (int ks = 0; ks < 4; ++ks) qf[ks] = *(const bf16x8*)(qp + ks * 32);
    }

    f32x4 o[8];
#pragma unroll
    for (int dt = 0; dt < 8; ++dt) o[dt] = zero4;
    float rsum = 0.f;

    __syncthreads();               // close previous phase's LDS use (incl. red overlay)
    stage(0, 0);

    for (int kt2 = 0; kt2 <= qt; ++kt2) {
      const int cur = kt2 & 1;
      __syncthreads();                              // group's buf 'cur' staged
      if (kt2 + 1 <= qt) stage(kt2 + 1, 1 - cur);   // prefetch behind this iteration

      // ---- S^T = K Q^T : rows = group's 32 keys, cols = wave's 16 q ----
      f32x4 s[2];
#pragma unroll
      for (int nt = 0; nt < 2; ++nt) {
        s[nt] = zero4;
#pragma unroll
        for (int ks = 0; ks < 4; ++ks) {
          const int ch = ks * 4 + quad;
          bf16x8 kf = *(const bf16x8*)&Ks[gid][cur][nt * 16 + l16][((ch & 8) | ((ch ^ l16) & 7)) * 8];
          s[nt] = __builtin_amdgcn_mfma_f32_16x16x32_bf16(kf, qf[ks], s[nt], 0, 0, 0);
        }
      }

      // ---- p = exp2(s*c1 - c2) ----
#pragma unroll
      for (int nt = 0; nt < 2; ++nt)
#pragma unroll
        for (int r = 0; r < 4; ++r)
          s[nt][r] = exp2f(fmaf(s[nt][r], c1, -c2));

      if (kt2 == qt) {               // diagonal tiles: ktg = 2qt+gid -> koff = gid*32
        const int koff = gid * 32;
        const int q_local = wq * 16 + l16;
#pragma unroll
        for (int nt = 0; nt < 2; ++nt)
#pragma unroll
          for (int r = 0; r < 4; ++r)
            if (koff + nt * 16 + quad * 4 + r > q_local) s[nt][r] = 0.f;
      }

      rsum += (s[0][0] + s[0][1]) + (s[0][2] + s[0][3]) +
              (s[1][0] + s[1][1]) + (s[1][2] + s[1][3]);

      // ---- P^T B-frag (K=32) via wave-local bpermute ----
      unsigned pk[2][2];
#pragma unroll
      for (int nt = 0; nt < 2; ++nt) {
        pk[nt][0] = pack2(s[nt][0], s[nt][1]);
        pk[nt][1] = pack2(s[nt][2], s[nt][3]);
      }
      int a0l = __builtin_amdgcn_ds_bpermute(addrA, (int)pk[0][0]);
      int a1l = __builtin_amdgcn_ds_bpermute(addrA, (int)pk[0][1]);
      int b0l = __builtin_amdgcn_ds_bpermute(addrB, (int)pk[0][0]);
      int b1l = __builtin_amdgcn_ds_bpermute(addrB, (int)pk[0][1]);
      int a0h = __builtin_amdgcn_ds_bpermute(addrA, (int)pk[1][0]);
      int a1h = __builtin_amdgcn_ds_bpermute(addrA, (int)pk[1][1]);
      int b0h = __builtin_amdgcn_ds_bpermute(addrB, (int)pk[1][0]);
      int b1h = __builtin_amdgcn_ds_bpermute(addrB, (int)pk[1][1]);
      union { int u[4]; bf16x8 v; } pf;
      pf.u[0] = hiq ? a0h : a0l;
      pf.u[1] = hiq ? a1h : a1l;
      pf.u[2] = hiq ? b0h : b0l;
      pf.u[3] = hiq ? b1h : b1l;

      // ---- O^T += V^T P^T  (A-frag: d = dt*16+l16, keys quad*8..+8) ----
#pragma unroll
      for (int dt = 0; dt < 8; ++dt) {
        const int d = dt * 16 + l16, row = d >> 1;
        const int slot = (quad ^ row) & 3;
        bf16x8 vf = *(const bf16x8*)&Vs[gid][cur][row][(d & 1) * 32 + slot * 8];
        o[dt] = __builtin_amdgcn_mfma_f32_16x16x32_bf16(vf, pf.v, o[dt], 0, 0, 0);
      }
    }

    // ---- epilogue: reduce rsum across quads, combine groups via LDS, store ----
    rsum += __shfl_xor(rsum, 16, 64);
    rsum += __shfl_xor(rsum, 32, 64);

    __syncthreads();               // all K-loop LDS reads done; red overlay safe
    if (gid == 1) {
#pragma unroll
      for (int dt = 0; dt < 8; ++dt)
        *(f32x4*)&red[(((wq * 8 + dt) * 64) + lane) * 4] = o[dt];
      if (quad == 0) rs1[wq * 16 + l16] = rsum;
    }
    __syncthreads();
    if (gid == 0) {
      const float inv = 1.0f / (rsum + rs1[wq * 16 + l16]);
      const int srow = qt * 64 + wq * 16 + l16;
      bf16* cp = ctx + (size_t)srow * HID + h * 128 + quad * 4;
#pragma unroll
      for (int dt = 0; dt < 8; ++dt) {
        f32x4 sum = o[dt] + *(const f32x4*)&red[(((wq * 8 + dt) * 64) + lane) * 4];
        union { bf16 hh[4]; uint2 u; } ov;
#pragma unroll
        for (int r = 0; r < 4; ++r) ov.hh[r] = __float2bfloat16(sum[r] * inv);
        *(uint2*)(cp + dt * 16) = ov.u;
      }
    }
  }
}

// ---------------- launcher ----------------
extern "C" void kernel_launch(void* const* d_in, const int* in_sizes, int n_in,
                              void* d_out, int out_size, void* d_ws, size_t ws_size,
                              hipStream_t stream) {
  const float* X  = (const float*)d_in[0];
  const float* Wq = (const float*)d_in[1];
  const float* bq = (const float*)d_in[2];
  const float* Wk = (const float*)d_in[3];
  const float* bk = (const float*)d_in[4];
  const float* Wv = (const float*)d_in[5];
  const float* bv = (const float*)d_in[6];
  const float* Wo = (const float*)d_in[7];
  const float* bo = (const float*)d_in[8];
  float* out = (float*)d_out;

  char* ws = (char*)d_ws;
  size_t off = 0;
  auto alloc = [&](size_t bytes) { char* p = ws + off; off += (bytes + 255) & ~255ULL; return p; };
  bf16*  Xb     = (bf16*) alloc((size_t)SEQ * HID * 2);
  bf16*  Wqkv_t = (bf16*) alloc((size_t)QKV_N * HID * 2);
  bf16*  Wot    = (bf16*) alloc((size_t)HID * HID * 2);
  float* bqkv   = (float*)alloc((size_t)QKV_N * 4);
  bf16*  QKV    = (bf16*) alloc((size_t)SEQ * QKV_N * 2);
  bf16*  Vt     = (bf16*) alloc((size_t)NG * DH * SEQ * 2);
  bf16*  Ctx    = (bf16*) alloc((size_t)SEQ * HID * 2);

  prepass_kernel<<<dim3(289, 64), 256, 0, stream>>>(X, Wq, Wk, Wv, Wo, bq, bk, bv,
                                                    Xb, Wqkv_t, Wot, bqkv);
  gemm10_kernel<256, bf16><<<dim3(QKV_N / 256, SEQ / 256), 512, 0, stream>>>(Xb, Wqkv_t, bqkv, QKV, SEQ, QKV_N, HID);
  rope_vtrans_kernel<<<2560 + 2048, 256, 0, stream>>>(QKV, Vt);
  attn_kernel<<<dim3(16, NH), 512, 0, stream>>>(QKV, Vt, Ctx);
  gemm10_kernel<128, float><<<dim3(HID / 256, SEQ / 128), 512, 0, stream>>>(Ctx, Wot, bo, out, SEQ, HID, HID);
}

// Round 7
// 499.789 us; speedup vs baseline: 1.0765x; 1.0765x over previous
//
#include <hip/hip_runtime.h>
#include <hip/hip_bf16.h>
#include <math.h>

#define HID   4096
#define NH    32
#define NG    8
#define DH    128
#define SEQ   2048
#define QKV_N 6144   // 4096 q | 1024 k | 1024 v
#define KOFF  4096
#define VOFF  5120

typedef __bf16 bf16x8 __attribute__((ext_vector_type(8)));
typedef float  f32x4  __attribute__((ext_vector_type(4)));
using bf16 = __hip_bfloat16;

#define LOG2E 1.4426950408889634f
#define SCALE 0.08838834764831845f   // 1/sqrt(128)

// ---- async global->LDS 16B (wave-uniform LDS base + lane*16) ----
typedef const __attribute__((address_space(1))) void* gas_p;
typedef __attribute__((address_space(3))) void* las_p;
__device__ __forceinline__ void async_copy16(void* lds, const void* g) {
  __builtin_amdgcn_global_load_lds((gas_p)g, (las_p)lds, 16, 0, 0);
}

__device__ __forceinline__ unsigned pack2(float a, float b) {
  union { bf16 h[2]; unsigned u; } t;
  t.h[0] = __float2bfloat16(a);
  t.h[1] = __float2bfloat16(b);
  return t.u;
}

// ---- unified prepass: weight transposes + X cast + bias concat, ONE launch ----
__global__ __launch_bounds__(256) void prepass_kernel(const float* __restrict__ X,
                                                      const float* __restrict__ Wq, const float* __restrict__ Wk,
                                                      const float* __restrict__ Wv, const float* __restrict__ Wo,
                                                      const float* __restrict__ bq, const float* __restrict__ bk,
                                                      const float* __restrict__ bv,
                                                      bf16* __restrict__ Xb,
                                                      bf16* __restrict__ Wqkv_t, bf16* __restrict__ Wot,
                                                      float* __restrict__ bqkv) {
  const int bx = blockIdx.x, by = blockIdx.y;
  const int t = threadIdx.x;
  if (bx >= 288) {               // bias concat
    if (by < 24) {
      int i = by * 256 + t;
      if (i < 4096)       bqkv[i] = bq[i];
      else if (i < 5120)  bqkv[i] = bk[i - 4096];
      else                bqkv[i] = bv[i - 5120];
    }
    return;
  }
  if (bx >= 160) {               // X cast: float4 per thread
    int i = ((bx - 160) + 128 * by) * 256 + t;
    float4 v = ((const float4*)X)[i];
    union { bf16 h[4]; uint2 u; } c;
    c.h[0] = __float2bfloat16(v.x);
    c.h[1] = __float2bfloat16(v.y);
    c.h[2] = __float2bfloat16(v.z);
    c.h[3] = __float2bfloat16(v.w);
    ((uint2*)Xb)[i] = c.u;
    return;
  }
  __shared__ bf16 T[64][72];
  const float* W; bf16* dst; int N, ntile;
  if (bx < 64)      { W = Wq; dst = Wqkv_t;                      N = 4096; ntile = bx; }
  else if (bx < 80) { W = Wk; dst = Wqkv_t + (size_t)KOFF * HID; N = 1024; ntile = bx - 64; }
  else if (bx < 96) { W = Wv; dst = Wqkv_t + (size_t)VOFF * HID; N = 1024; ntile = bx - 80; }
  else              { W = Wo; dst = Wot;                         N = 4096; ntile = bx - 96; }
  const int n0 = ntile * 64, k0 = by * 64;
  const int nn = (t & 15) * 4, kk = t >> 4;
#pragma unroll
  for (int p = 0; p < 4; ++p) {
    const int k = kk + p * 16;
    float4 v = *(const float4*)&W[(size_t)(k0 + k) * N + n0 + nn];
    union { bf16 h[4]; uint2 u; } c;
    c.h[0] = __float2bfloat16(v.x);
    c.h[1] = __float2bfloat16(v.y);
    c.h[2] = __float2bfloat16(v.z);
    c.h[3] = __float2bfloat16(v.w);
    *(uint2*)&T[k][nn] = c.u;
  }
  __syncthreads();
  const int kc = t & 7, nr = t >> 3;
#pragma unroll
  for (int p = 0; p < 2; ++p) {
    const int n = nr + p * 32;
    union { bf16 h[8]; uint4 u; } o;
#pragma unroll
    for (int i = 0; i < 8; ++i) o.h[i] = T[kc * 8 + i][n];
    *(uint4*)&dst[(size_t)(n0 + n) * HID + k0 + kc * 8] = o.u;
  }
}

// -- GEMM v6b: v3b skeleton, vmcnt cadence halved; LEDGER-CORRECT per-template waits --
// C[M][N] = A[M][K] @ Bt[N][K]^T + bias.  BN=256, BM in {256,128}. 512 thr = 8 waves
// (wr=w>>2 over M, wc=w&3 over N).  BK=64 split kh0/kh1; 4 phases per K-tile:
// P0=(kh0,n01)+ldA  P1=(kh0,n23)  P2=(kh1,n01)+ldA  P3=(kh1,n23); 2*MT MFMAs each.
// Staging: phase p of tile t stages one half of t+1 (P0:A-kh0, P1:B-kh0, P2:A-kh1,
// P3:B-kh1) into buf[(t+1)&1].  Per-phase load issue: BM=256 -> 2/2/2/2 (LA=2);
// BM=128 -> 1/2/1/2 (LA=1).
// Waits at P1-end and P3-end ONLY, vmcnt(LA+LB) -- the per-template HALF-TILE size:
//   BM=256: vmcnt(4).  Invariant: 4 in flight after each wait.
//     P1(t)-end: 8 outstanding, confirm {A-kh1,B-kh1}[t] -> read P2/P3(t).  OK
//     P3(t)-end: 8 outstanding, confirm {A-kh0,B-kh0}[t+1] -> read P0/P1(t+1). OK
//   BM=128: vmcnt(3).  Invariant: 3 in flight after each wait.
//     P1(t)-end: 6 outstanding, confirm {A-kh1(1),B-kh1(2)}[t].  OK
//     P3(t)-end: 6 outstanding, confirm {A-kh0(1),B-kh0(2)}[t+1]. OK
//   Prologue stages all 4 halves of tile 0 (8 resp. 6 outstanding); the same
//   vmcnt confirms exactly {A-kh0,B-kh0}[0] in both templates.
// (ROUND-6 BUG: vmcnt(4) hardcoded for BM=128 confirmed only 2 of B-kh0's 3-load
// half -> P0 ds_read raced the DMA -> nondeterministic out-proj (tripwire).  The
// wait count must equal the IN-FLIGHT half-tile loads of the SAME template.)
// P0/P2 keep both barriers (WAR epoch separation), no vmcnt.  vmcnt never 0 in
// the loop; vmcnt(0) drain before epilogue (no LDS-DMA in flight at s_endpgm).
// LDS swizzle: row r slot s holds global chunk s^((r>>1)&3); applied to the
// pre-swizzled global source (linear LDS-DMA dest) and the ds_read address.
// NO XCD block swizzle (round-5: FETCH 90->205 GB, destroys lockstep B-sharing).
__device__ __forceinline__ void st_out(float* C, size_t idx, float v) { C[idx] = v; }
__device__ __forceinline__ void st_out(bf16*  C, size_t idx, float v) { C[idx] = __float2bfloat16(v); }

template <int BM, typename OutT>
__global__ __launch_bounds__(512, 2) void gemm12_kernel(const bf16* __restrict__ A, const bf16* __restrict__ Bt,
                                                        const float* __restrict__ bias, OutT* __restrict__ C,
                                                        int M, int N, int K) {
  constexpr int MT = BM / 32;                        // M frags per wave (8 or 4)
  constexpr int LA = (BM * 32 * 2) / (512 * 16);     // A loads/thread per k-half (2 or 1)
  constexpr int LB = 2;                              // B loads/thread per k-half

  __shared__ alignas(16) bf16 As[2][2][BM * 32];     // [buf][kh][row*32 + slot*8]
  __shared__ alignas(16) bf16 Bs[2][2][256 * 32];

  const int tid = threadIdx.x;
  const int w = tid >> 6, lane = tid & 63, quad = lane >> 4, l16 = lane & 15;
  const int wr = w >> 2, wc = w & 3;
  const int m0 = blockIdx.y * BM, n0 = blockIdx.x * 256;

  const bf16* const Ag = A  + (size_t)m0 * K;
  const bf16* const Bg = Bt + (size_t)n0 * K;

  auto stA = [&](int skt, int db, int kh) {
    const int kb = skt * 64 + kh * 32;
#pragma unroll
    for (int L = 0; L < LA; ++L) {
      const int cib = (L * 8 + w) * 64;              // wave-uniform chunk base
      const int ci  = cib + lane;
      const int r   = ci >> 2;
      const int j   = (ci & 3) ^ ((r >> 1) & 3);     // inverse swizzle on source
      async_copy16(&As[db][kh][cib * 8], Ag + (size_t)r * K + kb + j * 8);
    }
  };
  auto stB = [&](int skt, int db, int kh) {
    const int kb = skt * 64 + kh * 32;
#pragma unroll
    for (int L = 0; L < LB; ++L) {
      const int cib = (L * 8 + w) * 64;
      const int ci  = cib + lane;
      const int r   = ci >> 2;
      const int j   = (ci & 3) ^ ((r >> 1) & 3);
      async_copy16(&Bs[db][kh][cib * 8], Bg + (size_t)r * K + kb + j * 8);
    }
  };

  auto waitv = [&]() {   // vmcnt(LA+LB): keep the newest half-tile in flight
    if constexpr (BM == 256) asm volatile("s_waitcnt vmcnt(4)" ::: "memory");
    else                     asm volatile("s_waitcnt vmcnt(3)" ::: "memory");
  };

  bf16x8 af[MT], bf2[2];
  auto ldA = [&](int buf, int kh) {
#pragma unroll
    for (int mf = 0; mf < MT; ++mf) {
      const int r = wr * (BM / 2) + mf * 16 + l16;
      af[mf] = *(const bf16x8*)&As[buf][kh][r * 32 + ((quad ^ ((r >> 1) & 3)) << 3)];
    }
  };
  auto ldB = [&](int buf, int kh, int ph) {
#pragma unroll
    for (int j = 0; j < 2; ++j) {
      const int r = wc * 64 + (ph * 2 + j) * 16 + l16;
      bf2[j] = *(const bf16x8*)&Bs[buf][kh][r * 32 + ((quad ^ ((r >> 1) & 3)) << 3)];
    }
  };

  f32x4 acc[MT][4];
  f32x4 zero4 = {0.f, 0.f, 0.f, 0.f};
#pragma unroll
  for (int mf = 0; mf < MT; ++mf)
#pragma unroll
    for (int nf = 0; nf < 4; ++nf) acc[mf][nf] = zero4;

#define GPHASE(BUF, KH, PH, DO_WAIT, STAGE_CALL)                                            \
  do {                                                                                      \
    if (PH == 0) ldA(BUF, KH);                                                              \
    ldB(BUF, KH, PH);                                                                       \
    STAGE_CALL;                                                                             \
    __builtin_amdgcn_s_barrier();                                                           \
    asm volatile("s_waitcnt lgkmcnt(0)" ::: "memory");                                      \
    __builtin_amdgcn_sched_barrier(0);                                                      \
    __builtin_amdgcn_s_setprio(1);                                                          \
    _Pragma("unroll")                                                                       \
    for (int mf = 0; mf < MT; ++mf) {                                                       \
      acc[mf][PH * 2 + 0] =                                                                 \
          __builtin_amdgcn_mfma_f32_16x16x32_bf16(af[mf], bf2[0], acc[mf][PH * 2 + 0], 0, 0, 0); \
      acc[mf][PH * 2 + 1] =                                                                 \
          __builtin_amdgcn_mfma_f32_16x16x32_bf16(af[mf], bf2[1], acc[mf][PH * 2 + 1], 0, 0, 0); \
    }                                                                                       \
    __builtin_amdgcn_s_setprio(0);                                                          \
    if (DO_WAIT) waitv();                                                                   \
    __builtin_amdgcn_s_barrier();                                                           \
    asm volatile("" ::: "memory");                                                          \
  } while (0)

  const int KT = K >> 6;                             // BK=64 tiles

  // prologue: stage all 4 halves of kt=0; waitv confirms exactly {A-kh0,B-kh0}[0]
  stA(0, 0, 0); stB(0, 0, 0); stA(0, 0, 1); stB(0, 0, 1);
  waitv();
  __builtin_amdgcn_s_barrier();
  asm volatile("" ::: "memory");

  for (int kt = 0; kt < KT; ++kt) {
    const int buf = kt & 1;
    const int nkt = kt + 1;
    const int skt = nkt < KT ? nkt : KT - 1;         // tail: redundant clamped stage keeps ledger uniform
    const int db  = nkt & 1;
    GPHASE(buf, 0, 0, false, stA(skt, db, 0));
    GPHASE(buf, 0, 1, true,  stB(skt, db, 0));
    GPHASE(buf, 1, 0, false, stA(skt, db, 1));
    GPHASE(buf, 1, 1, true,  stB(skt, db, 1));
  }
#undef GPHASE

  // drain LDS-DMA before epilogue: no in-flight global_load_lds at s_endpgm
  asm volatile("s_waitcnt vmcnt(0)" ::: "memory");

  // epilogue: bias + store (same fragment->C mapping as verified baseline)
#pragma unroll
  for (int nf = 0; nf < 4; ++nf) {
    const int col = n0 + wc * 64 + nf * 16 + l16;
    const float bv = bias[col];
#pragma unroll
    for (int mf = 0; mf < MT; ++mf) {
#pragma unroll
      for (int r = 0; r < 4; ++r) {
        const int row = m0 + wr * (BM / 2) + mf * 16 + quad * 4 + r;
        st_out(C, (size_t)row * N + col, acc[mf][nf][r] + bv);
      }
    }
  }
}

// ---- fused RoPE (q,k) + V transpose, one launch (disjoint QKV regions) ----
__global__ __launch_bounds__(256) void rope_vtrans_kernel(bf16* __restrict__ qkv, bf16* __restrict__ vt) {
  __shared__ bf16 tle[32][33];
  const int bx = blockIdx.x;
  const int tid = threadIdx.x;
  if (bx < 2560) {
    int t = bx * 256 + tid;
    int c  = t & 7;
    int hs = (t >> 3) % 40;
    int s  = t / 320;
    int base = (hs < 32) ? hs * 128 : KOFF + (hs - 32) * 128;
    bf16* p = qkv + (size_t)s * QKV_N + base + c * 8;
    union { bf16x8 v; bf16 h[8]; } a, b, ra, rb;
    a.v = *(bf16x8*)p;
    b.v = *(bf16x8*)(p + 64);
#pragma unroll
    for (int j = 0; j < 8; ++j) {
      int d = c * 8 + j;
      float inv = expf(d * -0.14391156862f);  // ln(10000)/64
      float ang = (float)s * inv;
      float sn, cs;
      sincosf(ang, &sn, &cs);
      float x1 = __bfloat162float(a.h[j]);
      float x2 = __bfloat162float(b.h[j]);
      ra.h[j] = __float2bfloat16(x1 * cs - x2 * sn);
      rb.h[j] = __float2bfloat16(x1 * sn + x2 * cs);
    }
    *(bf16x8*)p        = ra.v;
    *(bf16x8*)(p + 64) = rb.v;
  } else {
    const int b = bx - 2560;
    const int s0 = (b & 63) * 32, d0 = ((b >> 6) & 3) * 32, g = b >> 8;
    const int tx = tid & 31, ty = tid >> 5;
#pragma unroll
    for (int i = 0; i < 4; ++i)
      tle[ty + i * 8][tx] = qkv[(size_t)(s0 + ty + i * 8) * QKV_N + VOFF + g * 128 + d0 + tx];
    __syncthreads();
#pragma unroll
    for (int i = 0; i < 4; ++i)
      vt[(size_t)(g * 128 + d0 + ty + i * 8) * SEQ + s0 + tx] = tle[tx][ty + i * 8];
  }
}

// ---------------- Flash attention v5: in-block split-KV, 8 waves ----------------
__global__ __launch_bounds__(512, 4) void attn_kernel(const bf16* __restrict__ qkv, const bf16* __restrict__ vt,
                                                      bf16* __restrict__ ctx) {
  __shared__ alignas(16) bf16 Ks[2][2][32][128];  // [gid][buf][key][d] xor-swizzled; 32 KB
  __shared__ alignas(16) bf16 Vs[2][2][64][64];   // [gid][buf][d>>1][(d&1)*32+key] pair-packed; 32 KB
  __shared__ float rs1[64];
  float* const red = (float*)&Ks[0][0][0][0];     // epilogue overlay: 64q x 128d fp32 = 32 KB

  const int bx = blockIdx.x;        // 0..15
  const int h  = blockIdx.y;
  const int g  = h >> 2;
  const int tid = threadIdx.x;
  const int w = tid >> 6;           // 0..7
  const int gid = w >> 2, wq = w & 3;
  const int lane = tid & 63, quad = lane >> 4, l16 = lane & 15;

  const float c1 = SCALE * LOG2E;
  const float c2 = 12.0f * LOG2E;   // fixed max M0 = 12

  const int addrA = (((quad & 1) << 5) + l16) * 4;  // bpermute src (quad pair base)
  const int addrB = addrA + 64;
  const bool hiq = quad >= 2;

  f32x4 zero4 = {0.f, 0.f, 0.f, 0.f};

  auto stage = [&](int kt2, int buf) {
    const int ktg = 2 * kt2 + gid;
    const bf16* kg = qkv + (size_t)(ktg * 32) * QKV_N + KOFF + g * 128;
    const bf16* vg = vt + (size_t)(g * 128) * SEQ + ktg * 32;
#pragma unroll
    for (int i = 0; i < 2; ++i) {
      const int c = (i * 4 + wq) * 64 + lane;    // chunk 0..511
      {  // K: 32 keys x 16 chunks
        const int key = c >> 4, j = c & 15;
        const int js = (j & 8) | ((j ^ key) & 7);
        async_copy16(&Ks[gid][buf][0][0] + (size_t)(i * 4 + wq) * 512,
                     kg + (size_t)key * QKV_N + js * 8);
      }
      {  // V: 64 rows (d-pairs) x 8 chunks; slot k8s holds global chunk (k8s^row)&3
        const int row = c >> 3, d = row * 2 + ((c >> 2) & 1), k8s = c & 3;
        const int vjs = (k8s ^ row) & 3;
        async_copy16(&Vs[gid][buf][0][0] + (size_t)(i * 4 + wq) * 512,
                     vg + (size_t)d * SEQ + vjs * 8);
      }
    }
  };

  for (int ph = 0; ph < 2; ++ph) {
    const int qt = ph ? bx : (31 - bx);

    // Q fragments (B-operand): q = qt*64 + wq*16 + l16, k = ks*32 + quad*8 + j
    bf16x8 qf[4];
    {
      const bf16* qp = qkv + (size_t)(qt * 64 + wq * 16 + l16) * QKV_N + h * 128 + quad * 8;
#pragma unroll
      for (int ks = 0; ks < 4; ++ks) qf[ks] = *(const bf16x8*)(qp + ks * 32);
    }

    f32x4 o[8];
#pragma unroll
    for (int dt = 0; dt < 8; ++dt) o[dt] = zero4;
    float rsum = 0.f;

    __syncthreads();               // close previous phase's LDS use (incl. red overlay)
    stage(0, 0);

    for (int kt2 = 0; kt2 <= qt; ++kt2) {
      const int cur = kt2 & 1;
      __syncthreads();                              // group's buf 'cur' staged
      if (kt2 + 1 <= qt) stage(kt2 + 1, 1 - cur);   // prefetch behind this iteration

      // ---- S^T = K Q^T : rows = group's 32 keys, cols = wave's 16 q ----
      f32x4 s[2];
#pragma unroll
      for (int nt = 0; nt < 2; ++nt) {
        s[nt] = zero4;
#pragma unroll
        for (int ks = 0; ks < 4; ++ks) {
          const int ch = ks * 4 + quad;
          bf16x8 kf = *(const bf16x8*)&Ks[gid][cur][nt * 16 + l16][((ch & 8) | ((ch ^ l16) & 7)) * 8];
          s[nt] = __builtin_amdgcn_mfma_f32_16x16x32_bf16(kf, qf[ks], s[nt], 0, 0, 0);
        }
      }

      // ---- p = exp2(s*c1 - c2) ----
#pragma unroll
      for (int nt = 0; nt < 2; ++nt)
#pragma unroll
        for (int r = 0; r < 4; ++r)
          s[nt][r] = exp2f(fmaf(s[nt][r], c1, -c2));

      if (kt2 == qt) {               // diagonal tiles: ktg = 2qt+gid -> koff = gid*32
        const int koff = gid * 32;
        const int q_local = wq * 16 + l16;
#pragma unroll
        for (int nt = 0; nt < 2; ++nt)
#pragma unroll
          for (int r = 0; r < 4; ++r)
            if (koff + nt * 16 + quad * 4 + r > q_local) s[nt][r] = 0.f;
      }

      rsum += (s[0][0] + s[0][1]) + (s[0][2] + s[0][3]) +
              (s[1][0] + s[1][1]) + (s[1][2] + s[1][3]);

      // ---- P^T B-frag (K=32) via wave-local bpermute ----
      unsigned pk[2][2];
#pragma unroll
      for (int nt = 0; nt < 2; ++nt) {
        pk[nt][0] = pack2(s[nt][0], s[nt][1]);
        pk[nt][1] = pack2(s[nt][2], s[nt][3]);
      }
      int a0l = __builtin_amdgcn_ds_bpermute(addrA, (int)pk[0][0]);
      int a1l = __builtin_amdgcn_ds_bpermute(addrA, (int)pk[0][1]);
      int b0l = __builtin_amdgcn_ds_bpermute(addrB, (int)pk[0][0]);
      int b1l = __builtin_amdgcn_ds_bpermute(addrB, (int)pk[0][1]);
      int a0h = __builtin_amdgcn_ds_bpermute(addrA, (int)pk[1][0]);
      int a1h = __builtin_amdgcn_ds_bpermute(addrA, (int)pk[1][1]);
      int b0h = __builtin_amdgcn_ds_bpermute(addrB, (int)pk[1][0]);
      int b1h = __builtin_amdgcn_ds_bpermute(addrB, (int)pk[1][1]);
      union { int u[4]; bf16x8 v; } pf;
      pf.u[0] = hiq ? a0h : a0l;
      pf.u[1] = hiq ? a1h : a1l;
      pf.u[2] = hiq ? b0h : b0l;
      pf.u[3] = hiq ? b1h : b1l;

      // ---- O^T += V^T P^T  (A-frag: d = dt*16+l16, keys quad*8..+8) ----
#pragma unroll
      for (int dt = 0; dt < 8; ++dt) {
        const int d = dt * 16 + l16, row = d >> 1;
        const int slot = (quad ^ row) & 3;
        bf16x8 vf = *(const bf16x8*)&Vs[gid][cur][row][(d & 1) * 32 + slot * 8];
        o[dt] = __builtin_amdgcn_mfma_f32_16x16x32_bf16(vf, pf.v, o[dt], 0, 0, 0);
      }
    }

    // ---- epilogue: reduce rsum across quads, combine groups via LDS, store ----
    rsum += __shfl_xor(rsum, 16, 64);
    rsum += __shfl_xor(rsum, 32, 64);

    __syncthreads();               // all K-loop LDS reads done; red overlay safe
    if (gid == 1) {
#pragma unroll
      for (int dt = 0; dt < 8; ++dt)
        *(f32x4*)&red[(((wq * 8 + dt) * 64) + lane) * 4] = o[dt];
      if (quad == 0) rs1[wq * 16 + l16] = rsum;
    }
    __syncthreads();
    if (gid == 0) {
      const float inv = 1.0f / (rsum + rs1[wq * 16 + l16]);
      const int srow = qt * 64 + wq * 16 + l16;
      bf16* cp = ctx + (size_t)srow * HID + h * 128 + quad * 4;
#pragma unroll
      for (int dt = 0; dt < 8; ++dt) {
        f32x4 sum = o[dt] + *(const f32x4*)&red[(((wq * 8 + dt) * 64) + lane) * 4];
        union { bf16 hh[4]; uint2 u; } ov;
#pragma unroll
        for (int r = 0; r < 4; ++r) ov.hh[r] = __float2bfloat16(sum[r] * inv);
        *(uint2*)(cp + dt * 16) = ov.u;
      }
    }
  }
}

// ---------------- launcher ----------------
extern "C" void kernel_launch(void* const* d_in, const int* in_sizes, int n_in,
                              void* d_out, int out_size, void* d_ws, size_t ws_size,
                              hipStream_t stream) {
  const float* X  = (const float*)d_in[0];
  const float* Wq = (const float*)d_in[1];
  const float* bq = (const float*)d_in[2];
  const float* Wk = (const float*)d_in[3];
  const float* bk = (const float*)d_in[4];
  const float* Wv = (const float*)d_in[5];
  const float* bv = (const float*)d_in[6];
  const float* Wo = (const float*)d_in[7];
  const float* bo = (const float*)d_in[8];
  float* out = (float*)d_out;

  char* ws = (char*)d_ws;
  size_t off = 0;
  auto alloc = [&](size_t bytes) { char* p = ws + off; off += (bytes + 255) & ~255ULL; return p; };
  bf16*  Xb     = (bf16*) alloc((size_t)SEQ * HID * 2);
  bf16*  Wqkv_t = (bf16*) alloc((size_t)QKV_N * HID * 2);
  bf16*  Wot    = (bf16*) alloc((size_t)HID * HID * 2);
  float* bqkv   = (float*)alloc((size_t)QKV_N * 4);
  bf16*  QKV    = (bf16*) alloc((size_t)SEQ * QKV_N * 2);
  bf16*  Vt     = (bf16*) alloc((size_t)NG * DH * SEQ * 2);
  bf16*  Ctx    = (bf16*) alloc((size_t)SEQ * HID * 2);

  prepass_kernel<<<dim3(289, 64), 256, 0, stream>>>(X, Wq, Wk, Wv, Wo, bq, bk, bv,
                                                    Xb, Wqkv_t, Wot, bqkv);
  gemm12_kernel<256, bf16><<<dim3(QKV_N / 256, SEQ / 256), 512, 0, stream>>>(Xb, Wqkv_t, bqkv, QKV, SEQ, QKV_N, HID);
  rope_vtrans_kernel<<<2560 + 2048, 256, 0, stream>>>(QKV, Vt);
  attn_kernel<<<dim3(16, NH), 512, 0, stream>>>(QKV, Vt, Ctx);
  gemm12_kernel<128, float><<<dim3(HID / 256, SEQ / 128), 512, 0, stream>>>(Ctx, Wot, bo, out, SEQ, HID, HID);
}